// Round 12
// baseline (333.227 us; speedup 1.0000x reference)
//
#include <hip/hip_runtime.h>
#include <hip/hip_bf16.h>

#define NN 40000
#define NE 640000

typedef unsigned int u32;
typedef unsigned short u16;
typedef __attribute__((ext_vector_type(8))) short bf16x8;
typedef __attribute__((ext_vector_type(4))) float f32x4;

// ---------------- static device scratch (direct symbol use; no d_ws) -------
__device__ float g_wf[512];                  // biases + Wout + bout (f32)
__device__ u16   g_wp[40960];                // bf16 W1/W2/W3 in MFMA B-fragment layout
__device__ int   g_flags[4];                 // [0]=floats-are-f32, [1]=edge stride (1 or 2)
__device__ int   g_cnt[NN];
__device__ int   g_cur[NN];
__device__ int   g_rowptr[NN + 1];
__device__ float g_dinv[NN];
__device__ int   g_csrc[NE];
__device__ int   g_bsum[64];
__device__ int   g_bpre[64];
__device__ u16   g_ha[(size_t)NN * 128];     // bf16 A operand (x, then agg outputs)
__device__ u16   g_hb[(size_t)NN * 128];     // bf16 gemm output (gather operand)

// g_wf offsets
#define OFF_B1 0
#define OFF_B2 128
#define OFF_B3 256
#define OFF_WO 320
#define OFF_BO 448
// g_wp offsets
#define WP_W1 0
#define WP_W2 16384
#define WP_W3 32768

__device__ __forceinline__ float b2f(u16 v){ return __uint_as_float(((u32)v) << 16); }
__device__ __forceinline__ float blo(u32 u){ return __uint_as_float(u << 16); }
__device__ __forceinline__ float bhi(u32 u){ return __uint_as_float(u & 0xffff0000u); }
__device__ __forceinline__ u32 f2bf(float f){
  u32 u = __float_as_uint(f);
  return (u + 0x7fffu + ((u >> 16) & 1u)) >> 16;   // RNE
}
__device__ __forceinline__ int clampi(int v, int lo, int hi){ return v < lo ? lo : (v > hi ? hi : v); }
__device__ __forceinline__ u16 ldbf(const void* p, int idx){
  return g_flags[0] ? (u16)f2bf(((const float*)p)[idx]) : ((const u16*)p)[idx];
}
__device__ __forceinline__ float ldf(const void* p, int idx){
  return g_flags[0] ? ((const float*)p)[idx] : b2f(((const u16*)p)[idx]);
}

// ---- 0) runtime dtype detection ----
__global__ __launch_bounds__(256) void k_detect(const u16* __restrict__ xf, const int* __restrict__ ei){
  __shared__ int c1, c2;
  if (threadIdx.x == 0){ c1 = 0; c2 = 0; }
  __syncthreads();
  int l1 = 0, l2 = 0;
  for (int i = threadIdx.x; i < 4096; i += 256){
    u16 v = xf[2 * i];
    int e = (v >> 7) & 0xff;
    if (v == 0 || (e >= 100 && e <= 140)) l1++;
    if (ei[2 * i + 1] == 0) l2++;
  }
  atomicAdd(&c1, l1); atomicAdd(&c2, l2);
  __syncthreads();
  if (threadIdx.x == 0){
    g_flags[0] = (c1 < 2048) ? 1 : 0;
    g_flags[1] = (c2 > 2048) ? 2 : 1;
  }
}

// ---- 0b) fused preamble: cvt_x | packw | f32 table | zero counters | out=bias ----
__global__ __launch_bounds__(256) void k_prep(const void* xin, const void* w1, const void* b1,
                                              const void* w2, const void* b2, const void* w3,
                                              const void* b3, const void* wo, const void* bo,
                                              float* outp){
  int T = (int)blockIdx.x * 256 + (int)threadIdx.x;
  if (T < 640000){
    if (g_flags[0]){
      const float4* p = (const float4*)xin + (size_t)T * 2;
      float4 a = p[0], b = p[1];
      uint4 o;
      o.x = f2bf(a.x) | (f2bf(a.y) << 16);
      o.y = f2bf(a.z) | (f2bf(a.w) << 16);
      o.z = f2bf(b.x) | (f2bf(b.y) << 16);
      o.w = f2bf(b.z) | (f2bf(b.w) << 16);
      ((uint4*)g_ha)[T] = o;
    } else {
      ((uint4*)g_ha)[T] = ((const uint4*)xin)[T];
    }
  } else if (T < 680960){
    int local = T - 640000;
    int J, dstbase, l; const void* src;
    if (local < 16384){ J = 128; src = w1; dstbase = WP_W1; l = local; }
    else if (local < 32768){ J = 128; src = w2; dstbase = WP_W2; l = local - 16384; }
    else { J = 64; src = w3; dstbase = WP_W3; l = local - 32768; }
    int chunk = l >> 9, within = l & 511;
    int nbw = J / 16;
    int kb = chunk / nbw, nb = chunk % nbw;
    int lane = within >> 3, j = within & 7;
    int q = lane >> 4, n = lane & 15;
    int k = kb * 32 + q * 8 + j;
    int col = nb * 16 + n;
    g_wp[dstbase + l] = ldbf(src, k * J + col);
  } else if (T < 681410){
    int l = T - 680960;                      // 0..449
    if (l < 128)      g_wf[OFF_B1 + l] = ldf(b1, l);
    else if (l < 256) g_wf[OFF_B2 + l - 128] = ldf(b2, l - 128);
    else if (l < 320) g_wf[OFF_B3 + l - 256] = ldf(b3, l - 256);
    else if (l < 448) g_wf[OFF_WO + l - 320] = ldf(wo, l - 320);
    else              g_wf[OFF_BO + l - 448] = ldf(bo, l - 448);
  } else if (T < 721410){
    g_cnt[T - 681410] = 0;
  } else if (T < 761450){
    g_cur[T - 721410] = 0;
  } else if (T < 841450){
    int i = T - 761450;                      // out[N x 2] = bout (head partials add onto this)
    outp[i] = ldf(bo, i & 1);
  }
}

// ---- 1) in-degree count, XCD-partitioned ----
__global__ __launch_bounds__(256) void k_count(const int* __restrict__ ei){
  int part = (int)blockIdx.x & 7;
  int chunk = (int)blockIdx.x >> 3;
  int lo = part * 5000, hi = lo + 5000;
  int strd = g_flags[1];
  int tid = (int)threadIdx.x;
#pragma unroll
  for (int it = 0; it < 8; ++it){
    int e = chunk * 2048 + it * 256 + tid;
    if (e < NE){
      int d = clampi(ei[(size_t)(NE + e) * strd], 0, NN - 1);
      if (d >= lo && d < hi) atomicAdd(&g_cnt[d], 1);
    }
  }
}

// ---- 2a) block-level scan (40 blocks x 1024) ----
__global__ __launch_bounds__(1024) void k_scan1(){
  int t = (int)threadIdx.x;
  int b = (int)blockIdx.x;
  int i = b * 1024 + t;
  int v = (i < NN) ? g_cnt[i] : 0;
  int lane = t & 63, wv = t >> 6;
  int x = v;
#pragma unroll
  for (int ofs = 1; ofs < 64; ofs <<= 1){
    int y = __shfl_up(x, ofs, 64);
    if (lane >= ofs) x += y;
  }
  __shared__ int wsum[16];
  if (lane == 63) wsum[wv] = x;
  __syncthreads();
  if (t < 16){
    int s = wsum[t];
#pragma unroll
    for (int ofs = 1; ofs < 16; ofs <<= 1){
      int y = __shfl_up(s, ofs, 64);
      if (t >= ofs) s += y;
    }
    wsum[t] = s;
  }
  __syncthreads();
  int pre = (wv == 0) ? 0 : wsum[wv - 1];
  int incl = x + pre;
  if (i < NN){
    g_rowptr[i] = incl - v;
    g_dinv[i] = rsqrtf((float)(v + 1));
  }
  if (t == 1023) g_bsum[b] = incl;
}

// ---- 2b) scan 40 block sums ----
__global__ __launch_bounds__(64) void k_scan2(){
  int t = (int)threadIdx.x;
  int v = (t < 40) ? g_bsum[t] : 0;
  int s = v;
#pragma unroll
  for (int ofs = 1; ofs < 64; ofs <<= 1){
    int y = __shfl_up(s, ofs, 64);
    if (t >= ofs) s += y;
  }
  if (t < 40) g_bpre[t] = s - v;
  if (t == 39) g_rowptr[NN] = s;
}

// ---- 2c) add block offsets ----
__global__ __launch_bounds__(1024) void k_scan3(){
  int i = (int)blockIdx.x * 1024 + (int)threadIdx.x;
  if (i < NN) g_rowptr[i] += g_bpre[blockIdx.x];
}

// ---- 3) CSR scatter, XCD-partitioned ----
__global__ __launch_bounds__(256) void k_fill(const int* __restrict__ ei){
  int part = (int)blockIdx.x & 7;
  int chunk = (int)blockIdx.x >> 3;
  int lo = part * 5000, hi = lo + 5000;
  int strd = g_flags[1];
  int tid = (int)threadIdx.x;
#pragma unroll
  for (int it = 0; it < 8; ++it){
    int e = chunk * 2048 + it * 256 + tid;
    if (e < NE){
      int d = clampi(ei[(size_t)(NE + e) * strd], 0, NN - 1);
      if (d >= lo && d < hi){
        int s = clampi(ei[(size_t)e * strd], 0, NN - 1);
        int pos = clampi(g_rowptr[d] + atomicAdd(&g_cur[d], 1), 0, NE - 1);
        g_csrc[pos] = s;
      }
    }
  }
}

// ---- 4) MFMA GEMM: g_hb[N x J](bf16) = g_ha[N x 128](bf16) @ W(packed bf16) ----
template<int J>
__global__ __launch_bounds__(256) void k_gemm(int wpoff){
  constexpr int NB = J / 16;
  int tid = (int)threadIdx.x;
  int wave = tid >> 6, lane = tid & 63;
  int q = lane >> 4, n = lane & 15;
  int m0 = (int)blockIdx.x * 64 + wave * 16;
  f32x4 acc[NB];
#pragma unroll
  for (int nb = 0; nb < NB; ++nb) acc[nb] = (f32x4){0.f, 0.f, 0.f, 0.f};
  const u16* arow = g_ha + (size_t)(m0 + n) * 128 + q * 8;
#pragma unroll
  for (int kb = 0; kb < 4; ++kb){
    bf16x8 a = *(const bf16x8*)(arow + kb * 32);
    const u16* wbase = g_wp + wpoff + (kb * NB) * 512 + lane * 8;
#pragma unroll
    for (int nb = 0; nb < NB; ++nb){
      bf16x8 w = *(const bf16x8*)(wbase + nb * 512);
      acc[nb] = __builtin_amdgcn_mfma_f32_16x16x32_bf16(a, w, acc[nb], 0, 0, 0);
    }
  }
  u16* crow = g_hb + (size_t)(m0 + q * 4) * J + n;
#pragma unroll
  for (int r = 0; r < 4; ++r){
#pragma unroll
    for (int nb = 0; nb < NB; ++nb)
      crow[(size_t)r * J + nb * 16] = (u16)f2bf(acc[nb][r]);
  }
}

// ---- 5) Column-sliced CSR aggregation: slice = blockIdx % (J/32) -> 32-col (64B) slice ----
// Under %8 block->XCD round-robin each XCD gathers from a 2.56MB slice (L2-resident).
// Wave = 4 nodes x 16 lanes; lane = 2 bf16 cols (u32). 16 nodes/block, 2500*SLICES blocks.
template<int J, bool RELU>
__global__ __launch_bounds__(256) void k_agg(int boff, float* __restrict__ h3, float* __restrict__ outp){
  constexpr int SLICES = J / 32;
  int slice = (int)blockIdx.x & (SLICES - 1);
  int nblk  = (int)blockIdx.x >> (SLICES == 4 ? 2 : 1);
  int tid = (int)threadIdx.x;
  int wave = tid >> 6, lane = tid & 63;
  int grp = lane >> 4, l16 = lane & 15;
  int wid = nblk * 16 + wave * 4 + grp;          // 2500*16 == NN exactly
  int c = slice * 32 + l16 * 2;
  float di = g_dinv[wid];
  int beg = g_rowptr[wid], end = g_rowptr[wid + 1];
  float a0 = 0.f, a1 = 0.f;
  int e = beg;
  for (; e + 3 < end; e += 4){
    int s0 = clampi(g_csrc[e], 0, NN - 1);
    int s1 = clampi(g_csrc[e + 1], 0, NN - 1);
    int s2 = clampi(g_csrc[e + 2], 0, NN - 1);
    int s3 = clampi(g_csrc[e + 3], 0, NN - 1);
    u32 p0 = *(const u32*)(g_hb + (size_t)s0 * J + c);
    u32 p1 = *(const u32*)(g_hb + (size_t)s1 * J + c);
    u32 p2 = *(const u32*)(g_hb + (size_t)s2 * J + c);
    u32 p3 = *(const u32*)(g_hb + (size_t)s3 * J + c);
    float w0 = g_dinv[s0], w1 = g_dinv[s1], w2 = g_dinv[s2], w3 = g_dinv[s3];
    a0 = fmaf(w0, blo(p0), a0); a1 = fmaf(w0, bhi(p0), a1);
    a0 = fmaf(w1, blo(p1), a0); a1 = fmaf(w1, bhi(p1), a1);
    a0 = fmaf(w2, blo(p2), a0); a1 = fmaf(w2, bhi(p2), a1);
    a0 = fmaf(w3, blo(p3), a0); a1 = fmaf(w3, bhi(p3), a1);
  }
  for (; e < end; ++e){
    int s0 = clampi(g_csrc[e], 0, NN - 1);
    float w0 = g_dinv[s0];
    u32 p0 = *(const u32*)(g_hb + (size_t)s0 * J + c);
    a0 = fmaf(w0, blo(p0), a0); a1 = fmaf(w0, bhi(p0), a1);
  }
  u32 ps = *(const u32*)(g_hb + (size_t)wid * J + c);
  float sd = di * di;
  a0 = a0 * di + sd * blo(ps) + g_wf[boff + c];
  a1 = a1 * di + sd * bhi(ps) + g_wf[boff + c + 1];
  if (RELU){ a0 = fmaxf(a0, 0.f); a1 = fmaxf(a1, 0.f); }
  if (J == 128){
    *(u32*)(g_ha + (size_t)wid * 128 + c) = f2bf(a0) | (f2bf(a1) << 16);
  } else {
    *(float2*)(h3 + (size_t)wid * 64 + c) = make_float2(a0, a1);
    // fused head partial: this slice's 32-col contribution, 16-lane reduce, atomic add
    float o0 = a0 * g_wf[OFF_WO + c * 2]     + a1 * g_wf[OFF_WO + c * 2 + 2];
    float o1 = a0 * g_wf[OFF_WO + c * 2 + 1] + a1 * g_wf[OFF_WO + c * 2 + 3];
#pragma unroll
    for (int m = 1; m < 16; m <<= 1){
      o0 += __shfl_xor(o0, m, 64);
      o1 += __shfl_xor(o1, m, 64);
    }
    if (l16 == 0){
      atomicAdd(&outp[(size_t)wid * 2], o0);
      atomicAdd(&outp[(size_t)wid * 2 + 1], o1);
    }
  }
}

extern "C" void kernel_launch(void* const* d_in, const int* in_sizes, int n_in,
                              void* d_out, int out_size, void* d_ws, size_t ws_size,
                              hipStream_t stream){
  const int* ei = (const int*)d_in[1];
  float* out = (float*)d_out;                    // [N,2] then [N,64], f32
  float* h3  = out + (size_t)NN * 2;

  k_detect<<<1, 256, 0, stream>>>((const u16*)d_in[0], ei);
  k_prep<<<3287, 256, 0, stream>>>(d_in[0], d_in[2], d_in[3], d_in[4], d_in[5],
                                   d_in[6], d_in[7], d_in[8], d_in[9], out);
  k_count<<<2504, 256, 0, stream>>>(ei);
  k_scan1<<<40, 1024, 0, stream>>>();
  k_scan2<<<1, 64, 0, stream>>>();
  k_scan3<<<40, 1024, 0, stream>>>();
  k_fill<<<2504, 256, 0, stream>>>(ei);

  k_gemm<128><<<625, 256, 0, stream>>>(WP_W1);                               // g_ha -> g_hb
  k_agg<128, true><<<10000, 256, 0, stream>>>(OFF_B1, (float*)nullptr, (float*)nullptr);
  k_gemm<128><<<625, 256, 0, stream>>>(WP_W2);
  k_agg<128, true><<<10000, 256, 0, stream>>>(OFF_B2, (float*)nullptr, (float*)nullptr);
  k_gemm<64><<<625, 256, 0, stream>>>(WP_W3);                                // g_ha -> g_hb (N x 64)
  k_agg<64, false><<<5000, 256, 0, stream>>>(OFF_B3, h3, out);               // + fused head
}

// Round 13
// 259.908 us; speedup vs baseline: 1.2821x; 1.2821x over previous
//
#include <hip/hip_runtime.h>
#include <hip/hip_bf16.h>

#define NN 40000
#define NE 640000

typedef unsigned int u32;
typedef unsigned short u16;
typedef __attribute__((ext_vector_type(8))) short bf16x8;
typedef __attribute__((ext_vector_type(4))) float f32x4;

// ---------------- static device scratch (direct symbol use; no d_ws) -------
__device__ float g_wf[512];                  // biases + Wout + bout (f32)
__device__ u16   g_wp[40960];                // bf16 W1/W2/W3 in MFMA B-fragment layout
__device__ int   g_flags[4];                 // [0]=floats-are-f32, [1]=edge stride (1 or 2)
__device__ int   g_cnt[NN];
__device__ int   g_cur[NN];
__device__ int   g_rowptr[NN + 1];
__device__ float g_dinv[NN];
__device__ int   g_csrc[NE];
__device__ int   g_bsum[64];
__device__ u16   g_ha[(size_t)NN * 128];     // bf16 A operand (x, then agg outputs)
__device__ u16   g_hb[(size_t)NN * 128];     // bf16 gemm output, rows pre-scaled by dinv

// g_wf offsets
#define OFF_B1 0
#define OFF_B2 128
#define OFF_B3 256
#define OFF_WO 320
#define OFF_BO 448
// g_wp offsets
#define WP_W1 0
#define WP_W2 16384
#define WP_W3 32768

__device__ __forceinline__ float b2f(u16 v){ return __uint_as_float(((u32)v) << 16); }
__device__ __forceinline__ float blo(u32 u){ return __uint_as_float(u << 16); }
__device__ __forceinline__ float bhi(u32 u){ return __uint_as_float(u & 0xffff0000u); }
__device__ __forceinline__ u32 f2bf(float f){
  u32 u = __float_as_uint(f);
  return (u + 0x7fffu + ((u >> 16) & 1u)) >> 16;   // RNE
}
__device__ __forceinline__ int clampi(int v, int lo, int hi){ return v < lo ? lo : (v > hi ? hi : v); }
__device__ __forceinline__ u16 ldbf(const void* p, int idx){
  return g_flags[0] ? (u16)f2bf(((const float*)p)[idx]) : ((const u16*)p)[idx];
}
__device__ __forceinline__ float ldf(const void* p, int idx){
  return g_flags[0] ? ((const float*)p)[idx] : b2f(((const u16*)p)[idx]);
}

// ---- 0) runtime dtype detection ----
__global__ __launch_bounds__(256) void k_detect(const u16* __restrict__ xf, const int* __restrict__ ei){
  __shared__ int c1, c2;
  if (threadIdx.x == 0){ c1 = 0; c2 = 0; }
  __syncthreads();
  int l1 = 0, l2 = 0;
  for (int i = threadIdx.x; i < 4096; i += 256){
    u16 v = xf[2 * i];
    int e = (v >> 7) & 0xff;
    if (v == 0 || (e >= 100 && e <= 140)) l1++;
    if (ei[2 * i + 1] == 0) l2++;
  }
  atomicAdd(&c1, l1); atomicAdd(&c2, l2);
  __syncthreads();
  if (threadIdx.x == 0){
    g_flags[0] = (c1 < 2048) ? 1 : 0;
    g_flags[1] = (c2 > 2048) ? 2 : 1;
  }
}

// ---- 0b) fused preamble: cvt_x | packw | f32 table | zero counters ----
__global__ __launch_bounds__(256) void k_prep(const void* xin, const void* w1, const void* b1,
                                              const void* w2, const void* b2, const void* w3,
                                              const void* b3, const void* wo, const void* bo){
  int T = (int)blockIdx.x * 256 + (int)threadIdx.x;
  if (T < 640000){
    if (g_flags[0]){
      const float4* p = (const float4*)xin + (size_t)T * 2;
      float4 a = p[0], b = p[1];
      uint4 o;
      o.x = f2bf(a.x) | (f2bf(a.y) << 16);
      o.y = f2bf(a.z) | (f2bf(a.w) << 16);
      o.z = f2bf(b.x) | (f2bf(b.y) << 16);
      o.w = f2bf(b.z) | (f2bf(b.w) << 16);
      ((uint4*)g_ha)[T] = o;
    } else {
      ((uint4*)g_ha)[T] = ((const uint4*)xin)[T];
    }
  } else if (T < 680960){
    int local = T - 640000;
    int J, dstbase, l; const void* src;
    if (local < 16384){ J = 128; src = w1; dstbase = WP_W1; l = local; }
    else if (local < 32768){ J = 128; src = w2; dstbase = WP_W2; l = local - 16384; }
    else { J = 64; src = w3; dstbase = WP_W3; l = local - 32768; }
    int chunk = l >> 9, within = l & 511;
    int nbw = J / 16;
    int kb = chunk / nbw, nb = chunk % nbw;
    int lane = within >> 3, j = within & 7;
    int q = lane >> 4, n = lane & 15;
    int k = kb * 32 + q * 8 + j;
    int col = nb * 16 + n;
    g_wp[dstbase + l] = ldbf(src, k * J + col);
  } else if (T < 681410){
    int l = T - 680960;                      // 0..449
    if (l < 128)      g_wf[OFF_B1 + l] = ldf(b1, l);
    else if (l < 256) g_wf[OFF_B2 + l - 128] = ldf(b2, l - 128);
    else if (l < 320) g_wf[OFF_B3 + l - 256] = ldf(b3, l - 256);
    else if (l < 448) g_wf[OFF_WO + l - 320] = ldf(wo, l - 320);
    else              g_wf[OFF_BO + l - 448] = ldf(bo, l - 448);
  } else if (T < 721410){
    g_cnt[T - 681410] = 0;
  } else if (T < 761450){
    g_cur[T - 721410] = 0;
  }
}

// ---- 1) in-degree count (simple; atomic table is L2-resident) ----
__global__ __launch_bounds__(256) void k_count(const int* __restrict__ ei){
  int e = blockIdx.x * 256 + threadIdx.x;
  if (e < NE){
    int strd = g_flags[1];
    int d = clampi(ei[(size_t)(NE + e) * strd], 0, NN - 1);
    atomicAdd(&g_cnt[d], 1);
  }
}

// ---- 2a) block-level scan (40 blocks x 1024): local exclusive + block sums ----
__global__ __launch_bounds__(1024) void k_scan1(){
  int t = (int)threadIdx.x;
  int b = (int)blockIdx.x;
  int i = b * 1024 + t;
  int v = (i < NN) ? g_cnt[i] : 0;
  int lane = t & 63, wv = t >> 6;
  int x = v;
#pragma unroll
  for (int ofs = 1; ofs < 64; ofs <<= 1){
    int y = __shfl_up(x, ofs, 64);
    if (lane >= ofs) x += y;
  }
  __shared__ int wsum[16];
  if (lane == 63) wsum[wv] = x;
  __syncthreads();
  if (t < 16){
    int s = wsum[t];
#pragma unroll
    for (int ofs = 1; ofs < 16; ofs <<= 1){
      int y = __shfl_up(s, ofs, 64);
      if (t >= ofs) s += y;
    }
    wsum[t] = s;
  }
  __syncthreads();
  int pre = (wv == 0) ? 0 : wsum[wv - 1];
  int incl = x + pre;
  if (i < NN){
    g_rowptr[i] = incl - v;
    g_dinv[i] = rsqrtf((float)(v + 1));
  }
  if (t == 1023) g_bsum[b] = incl;
}

// ---- 2b) add block offsets (block-sum scan inlined in wave 0 of every block) ----
__global__ __launch_bounds__(1024) void k_scan3(){
  __shared__ int pre;
  int t = (int)threadIdx.x;
  if (t < 64){
    int v = (t < 40) ? g_bsum[t] : 0;
    int s = v;
#pragma unroll
    for (int ofs = 1; ofs < 64; ofs <<= 1){
      int y = __shfl_up(s, ofs, 64);
      if (t >= ofs) s += y;
    }
    if (t == (int)blockIdx.x) pre = s - v;               // exclusive prefix for this block
    if (blockIdx.x == 0 && t == 39) g_rowptr[NN] = s;    // grand total
  }
  __syncthreads();
  int i = (int)blockIdx.x * 1024 + t;
  if (i < NN) g_rowptr[i] += pre;
}

// ---- 3) CSR scatter, dst-partitioned (writes confined to 320KB window/partition) ----
__global__ __launch_bounds__(256) void k_fill(const int* __restrict__ ei){
  int part = (int)blockIdx.x & 7;
  int chunk = (int)blockIdx.x >> 3;
  int lo = part * 5000, hi = lo + 5000;
  int strd = g_flags[1];
  int tid = (int)threadIdx.x;
#pragma unroll
  for (int it = 0; it < 8; ++it){
    int e = chunk * 2048 + it * 256 + tid;
    if (e < NE){
      int d = clampi(ei[(size_t)(NE + e) * strd], 0, NN - 1);
      if (d >= lo && d < hi){
        int s = clampi(ei[(size_t)e * strd], 0, NN - 1);
        int pos = clampi(g_rowptr[d] + atomicAdd(&g_cur[d], 1), 0, NE - 1);
        g_csrc[pos] = s;
      }
    }
  }
}

// ---- 4) MFMA GEMM: g_hb[r] = dinv[r] * (g_ha[r] @ W)   (bf16 out, rows pre-scaled) ----
template<int J>
__global__ __launch_bounds__(256) void k_gemm(int wpoff){
  constexpr int NB = J / 16;
  int tid = (int)threadIdx.x;
  int wave = tid >> 6, lane = tid & 63;
  int q = lane >> 4, n = lane & 15;
  int m0 = (int)blockIdx.x * 64 + wave * 16;
  f32x4 acc[NB];
#pragma unroll
  for (int nb = 0; nb < NB; ++nb) acc[nb] = (f32x4){0.f, 0.f, 0.f, 0.f};
  const u16* arow = g_ha + (size_t)(m0 + n) * 128 + q * 8;
#pragma unroll
  for (int kb = 0; kb < 4; ++kb){
    bf16x8 a = *(const bf16x8*)(arow + kb * 32);
    const u16* wbase = g_wp + wpoff + (kb * NB) * 512 + lane * 8;
#pragma unroll
    for (int nb = 0; nb < NB; ++nb){
      bf16x8 w = *(const bf16x8*)(wbase + nb * 512);
      acc[nb] = __builtin_amdgcn_mfma_f32_16x16x32_bf16(a, w, acc[nb], 0, 0, 0);
    }
  }
  u16* crow = g_hb + (size_t)(m0 + q * 4) * J + n;
#pragma unroll
  for (int r = 0; r < 4; ++r){
    float di = g_dinv[m0 + q * 4 + r];
#pragma unroll
    for (int nb = 0; nb < NB; ++nb)
      crow[(size_t)r * J + nb * 16] = (u16)f2bf(acc[nb][r] * di);
  }
}

// ---- 5) CSR aggregation on pre-scaled rows: out = di*(sum_e h'[s] + h'[i]) + b ----
// 2 nodes/wave, half-wave/node, 8x unroll. J=64 fuses output head.
template<int J, bool RELU>
__global__ __launch_bounds__(256) void k_agg(int boff, float* __restrict__ h3, float* __restrict__ outp){
  int wpair = (int)((blockIdx.x * 256 + threadIdx.x) >> 6);
  int lane = (int)threadIdx.x & 63;
  int sub = lane >> 5, sl = lane & 31;
  int wid = wpair * 2 + sub;
  if (wid >= NN) return;
  float di = g_dinv[wid];
  int beg = g_rowptr[wid], end = g_rowptr[wid + 1];
  if (J == 128){
    int cc = sl * 4;
    float a0 = 0.f, a1 = 0.f, a2 = 0.f, a3 = 0.f;
    int e = beg;
    for (; e + 7 < end; e += 8){
      int s[8]; uint2 p[8];
#pragma unroll
      for (int t = 0; t < 8; ++t) s[t] = clampi(g_csrc[e + t], 0, NN - 1);
#pragma unroll
      for (int t = 0; t < 8; ++t) p[t] = *(const uint2*)(g_hb + (size_t)s[t] * 128 + cc);
#pragma unroll
      for (int t = 0; t < 8; ++t){
        a0 += blo(p[t].x); a1 += bhi(p[t].x);
        a2 += blo(p[t].y); a3 += bhi(p[t].y);
      }
    }
    for (; e < end; ++e){
      int s0 = clampi(g_csrc[e], 0, NN - 1);
      uint2 p0 = *(const uint2*)(g_hb + (size_t)s0 * 128 + cc);
      a0 += blo(p0.x); a1 += bhi(p0.x);
      a2 += blo(p0.y); a3 += bhi(p0.y);
    }
    uint2 ps = *(const uint2*)(g_hb + (size_t)wid * 128 + cc);   // self term h'[i]
    a0 += blo(ps.x); a1 += bhi(ps.x);
    a2 += blo(ps.y); a3 += bhi(ps.y);
    a0 = a0 * di + g_wf[boff + cc];
    a1 = a1 * di + g_wf[boff + cc + 1];
    a2 = a2 * di + g_wf[boff + cc + 2];
    a3 = a3 * di + g_wf[boff + cc + 3];
    if (RELU){
      a0 = fmaxf(a0, 0.f); a1 = fmaxf(a1, 0.f);
      a2 = fmaxf(a2, 0.f); a3 = fmaxf(a3, 0.f);
    }
    uint2 o;
    o.x = f2bf(a0) | (f2bf(a1) << 16);
    o.y = f2bf(a2) | (f2bf(a3) << 16);
    *(uint2*)(g_ha + (size_t)wid * 128 + cc) = o;
  } else {
    int cc = sl * 2;
    float a0 = 0.f, a1 = 0.f;
    int e = beg;
    for (; e + 7 < end; e += 8){
      int s[8]; u32 p[8];
#pragma unroll
      for (int t = 0; t < 8; ++t) s[t] = clampi(g_csrc[e + t], 0, NN - 1);
#pragma unroll
      for (int t = 0; t < 8; ++t) p[t] = *(const u32*)(g_hb + (size_t)s[t] * 64 + cc);
#pragma unroll
      for (int t = 0; t < 8; ++t){ a0 += blo(p[t]); a1 += bhi(p[t]); }
    }
    for (; e < end; ++e){
      int s0 = clampi(g_csrc[e], 0, NN - 1);
      u32 p0 = *(const u32*)(g_hb + (size_t)s0 * 64 + cc);
      a0 += blo(p0); a1 += bhi(p0);
    }
    u32 ps = *(const u32*)(g_hb + (size_t)wid * 64 + cc);        // self term
    a0 += blo(ps); a1 += bhi(ps);
    a0 = a0 * di + g_wf[boff + cc];
    a1 = a1 * di + g_wf[boff + cc + 1];
    if (RELU){ a0 = fmaxf(a0, 0.f); a1 = fmaxf(a1, 0.f); }
    *(float2*)(h3 + (size_t)wid * 64 + cc) = make_float2(a0, a1);
    // fused output head: out[wid] = h3row @ Wout + bout, 32-lane shuffle reduce
    float o0 = a0 * g_wf[OFF_WO + cc * 2]     + a1 * g_wf[OFF_WO + cc * 2 + 2];
    float o1 = a0 * g_wf[OFF_WO + cc * 2 + 1] + a1 * g_wf[OFF_WO + cc * 2 + 3];
#pragma unroll
    for (int m = 1; m < 32; m <<= 1){
      o0 += __shfl_xor(o0, m, 64);
      o1 += __shfl_xor(o1, m, 64);
    }
    if (sl == 0){
      *(float2*)(outp + (size_t)wid * 2) =
        make_float2(o0 + g_wf[OFF_BO], o1 + g_wf[OFF_BO + 1]);
    }
  }
}

extern "C" void kernel_launch(void* const* d_in, const int* in_sizes, int n_in,
                              void* d_out, int out_size, void* d_ws, size_t ws_size,
                              hipStream_t stream){
  const int* ei = (const int*)d_in[1];
  float* out = (float*)d_out;                    // [N,2] then [N,64], f32
  float* h3  = out + (size_t)NN * 2;

  k_detect<<<1, 256, 0, stream>>>((const u16*)d_in[0], ei);
  k_prep<<<2975, 256, 0, stream>>>(d_in[0], d_in[2], d_in[3], d_in[4], d_in[5],
                                   d_in[6], d_in[7], d_in[8], d_in[9]);
  k_count<<<2500, 256, 0, stream>>>(ei);
  k_scan1<<<40, 1024, 0, stream>>>();
  k_scan3<<<40, 1024, 0, stream>>>();
  k_fill<<<2504, 256, 0, stream>>>(ei);

  k_gemm<128><<<625, 256, 0, stream>>>(WP_W1);                               // g_ha -> g_hb (scaled)
  k_agg<128, true><<<5000, 256, 0, stream>>>(OFF_B1, (float*)nullptr, (float*)nullptr);
  k_gemm<128><<<625, 256, 0, stream>>>(WP_W2);
  k_agg<128, true><<<5000, 256, 0, stream>>>(OFF_B2, (float*)nullptr, (float*)nullptr);
  k_gemm<64><<<625, 256, 0, stream>>>(WP_W3);                                // g_ha -> g_hb (N x 64)
  k_agg<64, false><<<5000, 256, 0, stream>>>(OFF_B3, h3, out);               // + fused head
}